// Round 7
// baseline (176.419 us; speedup 1.0000x reference)
//
#include <hip/hip_runtime.h>

// PRNNCell: B=64, I=512, H=1024, D=1536
//   x = concat(inputs, hidden)                       (B, D)
//   new_hidden = tanh(einsum('bd,bhd->bh', x, wih) + bih)
//   new_wih = wih + y*x*Wa + x*Wb + y*Wc + Wd        (y = new_hidden[b,h])
//   (dop in the reference is dead code -> skipped)
//
// R7 = R3 structure (162.9 us known-good) with NT hints REMOVED (plain cached
// loads/stores) to test whether nontemporal policy was costing HBM BW vs the
// 6.29 TB/s cached-copy ceiling. fast_tanh kept (validated R5).
// History: R4 2-deep pipeline = neutral; R5 launch_bounds(512,8) = VGPR 32 +
// spills, 443 us (never force min-waves here); R6 XCD swizzle = -4.5% (no
// inter-block operand sharing to exploit).

#define BB 64
#define II 512
#define HH 1024
#define DD 1536
#define NF4 (DD / 4)          // 384 vec4 per row
#define THREADS 512
#define PER_WAVE (BB / 8)     // 8 rows per wave

typedef float f4 __attribute__((ext_vector_type(4)));

__device__ __forceinline__ float fast_tanh(float x) {
    // exp overflow -> inf -> 2/inf = 0 -> y=1; underflow -> e=0 -> y=-1.
    const float e = __expf(2.0f * x);
    return 1.0f - 2.0f / (1.0f + e);
}

__global__ __launch_bounds__(THREADS) void prnn_fused(
    const float* __restrict__ inputs,   // B x I
    const float* __restrict__ hidden,   // B x H
    const float* __restrict__ wih,      // B x H x D
    const float* __restrict__ Wa,       // H x D
    const float* __restrict__ Wb,
    const float* __restrict__ Wc,
    const float* __restrict__ Wd,
    const float* __restrict__ bih,      // H
    float* __restrict__ out_h,          // B x H
    float* __restrict__ out_w)          // B x H x D
{
    __shared__ f4 sA[NF4], sB[NF4], sC[NF4], sD[NF4];   // 24 KB

    const int h    = blockIdx.x;
    const int tid  = threadIdx.x;
    const int lane = tid & 63;
    const int wid  = tid >> 6;

    if (tid < NF4) {
        sA[tid] = ((const f4*)(Wa + (size_t)h * DD))[tid];
        sB[tid] = ((const f4*)(Wb + (size_t)h * DD))[tid];
        sC[tid] = ((const f4*)(Wc + (size_t)h * DD))[tid];
        sD[tid] = ((const f4*)(Wd + (size_t)h * DD))[tid];
    }
    const float bh = bih[h];
    __syncthreads();

    for (int i = 0; i < PER_WAVE; ++i) {
        const int b    = wid * PER_WAVE + i;            // wave-uniform
        const size_t r = (size_t)b * HH + h;
        const f4* __restrict__ wrow = (const f4*)(wih + r * DD);
        const f4* __restrict__ xin  = (const f4*)(inputs + (size_t)b * II);
        const f4* __restrict__ xhi  = (const f4*)(hidden + (size_t)b * HH);

        // Phase 1: stream wih row into regs, dot with x (x not kept live).
        f4 wv[6];
        float dot = 0.f;
#pragma unroll
        for (int k = 0; k < 6; ++k) {
            const int j = lane + 64 * k;                // 0..383
            wv[k] = wrow[j];
            const f4 xk = (k < 2) ? xin[j] : xhi[j - 128];
            dot += xk.x * wv[k].x + xk.y * wv[k].y
                 + xk.z * wv[k].z + xk.w * wv[k].w;
        }
#pragma unroll
        for (int off = 32; off >= 1; off >>= 1)
            dot += __shfl_xor(dot, off, 64);
        const float y = fast_tanh(dot + bh);
        if (lane == 0) out_h[r] = y;

        // Phase 2: update from LDS + regs; x re-read (L1/L2-hot).
        f4* __restrict__ orow = (f4*)(out_w + r * DD);
#pragma unroll
        for (int k = 0; k < 6; ++k) {
            const int j = lane + 64 * k;
            const f4 xk = (k < 2) ? xin[j] : xhi[j - 128];
            const f4 a  = sA[j];
            const f4 b2 = sB[j];
            const f4 c  = sC[j];
            const f4 d  = sD[j];
            f4 o;
            o.x = wv[k].x + xk.x * fmaf(y, a.x, b2.x) + fmaf(y, c.x, d.x);
            o.y = wv[k].y + xk.y * fmaf(y, a.y, b2.y) + fmaf(y, c.y, d.y);
            o.z = wv[k].z + xk.z * fmaf(y, a.z, b2.z) + fmaf(y, c.z, d.z);
            o.w = wv[k].w + xk.w * fmaf(y, a.w, b2.w) + fmaf(y, c.w, d.w);
            orow[j] = o;
        }
    }
}

extern "C" void kernel_launch(void* const* d_in, const int* in_sizes, int n_in,
                              void* d_out, int out_size, void* d_ws, size_t ws_size,
                              hipStream_t stream) {
    const float* inputs = (const float*)d_in[0];
    const float* hidden = (const float*)d_in[1];
    const float* wih    = (const float*)d_in[2];
    const float* Wa     = (const float*)d_in[3];
    const float* Wb     = (const float*)d_in[4];
    const float* Wc     = (const float*)d_in[5];
    const float* Wd     = (const float*)d_in[6];
    const float* bih    = (const float*)d_in[7];
    // d_in[8] = W_dop, d_in[9] = b_dop: dead code in the reference, unused.

    float* out   = (float*)d_out;
    float* out_h = out;                    // B*H floats
    float* out_w = out + (size_t)BB * HH;  // B*H*D floats

    dim3 grid(HH), block(THREADS);
    prnn_fused<<<grid, block, 0, stream>>>(inputs, hidden, wih, Wa, Wb, Wc, Wd,
                                           bih, out_h, out_w);
}

// Round 8
// 167.109 us; speedup vs baseline: 1.0557x; 1.0557x over previous
//
#include <hip/hip_runtime.h>

// PRNNCell: B=64, I=512, H=1024, D=1536
//   x = concat(inputs, hidden)                       (B, D)
//   new_hidden = tanh(einsum('bd,bhd->bh', x, wih) + bih)
//   new_wih = wih + y*x*Wa + x*Wb + y*Wc + Wd        (y = new_hidden[b,h])
//   (dop in the reference is dead code -> skipped)
//
// R8 = R3 (one block per h, Wa..d in 24 KB LDS, wih NT-streamed once,
// x re-read in phase 2 from L2, natural VGPR) + ROW-PAIR processing:
// both rows' 12 KB of loads in flight together, the two shfl-reduce chains
// interleaved (independent -> dual-issue, halves serial stall per row),
// updates+stores emitted as one 12 KB write burst (less DRAM r/w turnaround).
// Ledger: R4 2-deep pipeline neutral; R5 forced min-waves=8 -> VGPR32+spill
// (443us, never again); R6 XCD swizzle -4.5%; R7 cached (no NT) -8%.

#define BB 64
#define II 512
#define HH 1024
#define DD 1536
#define NF4 (DD / 4)          // 384 vec4 per row
#define THREADS 512
#define PER_WAVE (BB / 8)     // 8 rows per wave

typedef float f4 __attribute__((ext_vector_type(4)));

__device__ __forceinline__ float fast_tanh(float x) {
    // exp overflow -> inf -> 2/inf = 0 -> y=1; underflow -> e=0 -> y=-1.
    const float e = __expf(2.0f * x);
    return 1.0f - 2.0f / (1.0f + e);
}

__global__ __launch_bounds__(THREADS) void prnn_fused(
    const float* __restrict__ inputs,   // B x I
    const float* __restrict__ hidden,   // B x H
    const float* __restrict__ wih,      // B x H x D
    const float* __restrict__ Wa,       // H x D
    const float* __restrict__ Wb,
    const float* __restrict__ Wc,
    const float* __restrict__ Wd,
    const float* __restrict__ bih,      // H
    float* __restrict__ out_h,          // B x H
    float* __restrict__ out_w)          // B x H x D
{
    __shared__ f4 sA[NF4], sB[NF4], sC[NF4], sD[NF4];   // 24 KB

    const int h    = blockIdx.x;
    const int tid  = threadIdx.x;
    const int lane = tid & 63;
    const int wid  = tid >> 6;

    if (tid < NF4) {
        sA[tid] = ((const f4*)(Wa + (size_t)h * DD))[tid];
        sB[tid] = ((const f4*)(Wb + (size_t)h * DD))[tid];
        sC[tid] = ((const f4*)(Wc + (size_t)h * DD))[tid];
        sD[tid] = ((const f4*)(Wd + (size_t)h * DD))[tid];
    }
    const float bh = bih[h];
    __syncthreads();

    for (int i = 0; i < PER_WAVE; i += 2) {
        const int b0 = wid * PER_WAVE + i;              // wave-uniform
        const int b1 = b0 + 1;
        const size_t r0 = (size_t)b0 * HH + h;
        const size_t r1 = (size_t)b1 * HH + h;
        const f4* __restrict__ wrow0 = (const f4*)(wih + r0 * DD);
        const f4* __restrict__ wrow1 = (const f4*)(wih + r1 * DD);
        const f4* __restrict__ xin0  = (const f4*)(inputs + (size_t)b0 * II);
        const f4* __restrict__ xhi0  = (const f4*)(hidden + (size_t)b0 * HH);
        const f4* __restrict__ xin1  = (const f4*)(inputs + (size_t)b1 * II);
        const f4* __restrict__ xhi1  = (const f4*)(hidden + (size_t)b1 * HH);

        // Phase 1: both rows' loads issued together (12 KB read burst).
        f4 wv0[6], wv1[6];
#pragma unroll
        for (int k = 0; k < 6; ++k) {
            const int j = lane + 64 * k;
            wv0[k] = __builtin_nontemporal_load(&wrow0[j]);
            wv1[k] = __builtin_nontemporal_load(&wrow1[j]);
        }
        float dot0 = 0.f, dot1 = 0.f;
#pragma unroll
        for (int k = 0; k < 6; ++k) {
            const int j = lane + 64 * k;
            const f4 x0 = (k < 2) ? xin0[j] : xhi0[j - 128];
            const f4 x1 = (k < 2) ? xin1[j] : xhi1[j - 128];
            dot0 += x0.x * wv0[k].x + x0.y * wv0[k].y
                  + x0.z * wv0[k].z + x0.w * wv0[k].w;
            dot1 += x1.x * wv1[k].x + x1.y * wv1[k].y
                  + x1.z * wv1[k].z + x1.w * wv1[k].w;
        }

        // Interleaved butterfly reduces: two independent chains dual-issue.
#pragma unroll
        for (int off = 32; off >= 1; off >>= 1) {
            dot0 += __shfl_xor(dot0, off, 64);
            dot1 += __shfl_xor(dot1, off, 64);
        }
        const float y0 = fast_tanh(dot0 + bh);
        const float y1 = fast_tanh(dot1 + bh);
        if (lane == 0) { out_h[r0] = y0; out_h[r1] = y1; }

        // Phase 2: both updates, stores back-to-back (12 KB write burst).
        f4* __restrict__ orow0 = (f4*)(out_w + r0 * DD);
        f4* __restrict__ orow1 = (f4*)(out_w + r1 * DD);
#pragma unroll
        for (int k = 0; k < 6; ++k) {
            const int j = lane + 64 * k;
            const f4 a  = sA[j];
            const f4 b2 = sB[j];
            const f4 c  = sC[j];
            const f4 d  = sD[j];
            const f4 x0 = (k < 2) ? xin0[j] : xhi0[j - 128];
            const f4 x1 = (k < 2) ? xin1[j] : xhi1[j - 128];
            f4 o0, o1;
            o0.x = wv0[k].x + x0.x * fmaf(y0, a.x, b2.x) + fmaf(y0, c.x, d.x);
            o0.y = wv0[k].y + x0.y * fmaf(y0, a.y, b2.y) + fmaf(y0, c.y, d.y);
            o0.z = wv0[k].z + x0.z * fmaf(y0, a.z, b2.z) + fmaf(y0, c.z, d.z);
            o0.w = wv0[k].w + x0.w * fmaf(y0, a.w, b2.w) + fmaf(y0, c.w, d.w);
            o1.x = wv1[k].x + x1.x * fmaf(y1, a.x, b2.x) + fmaf(y1, c.x, d.x);
            o1.y = wv1[k].y + x1.y * fmaf(y1, a.y, b2.y) + fmaf(y1, c.y, d.y);
            o1.z = wv1[k].z + x1.z * fmaf(y1, a.z, b2.z) + fmaf(y1, c.z, d.z);
            o1.w = wv1[k].w + x1.w * fmaf(y1, a.w, b2.w) + fmaf(y1, c.w, d.w);
            __builtin_nontemporal_store(o0, &orow0[j]);
            __builtin_nontemporal_store(o1, &orow1[j]);
        }
    }
}

extern "C" void kernel_launch(void* const* d_in, const int* in_sizes, int n_in,
                              void* d_out, int out_size, void* d_ws, size_t ws_size,
                              hipStream_t stream) {
    const float* inputs = (const float*)d_in[0];
    const float* hidden = (const float*)d_in[1];
    const float* wih    = (const float*)d_in[2];
    const float* Wa     = (const float*)d_in[3];
    const float* Wb     = (const float*)d_in[4];
    const float* Wc     = (const float*)d_in[5];
    const float* Wd     = (const float*)d_in[6];
    const float* bih    = (const float*)d_in[7];
    // d_in[8] = W_dop, d_in[9] = b_dop: dead code in the reference, unused.

    float* out   = (float*)d_out;
    float* out_h = out;                    // B*H floats
    float* out_w = out + (size_t)BB * HH;  // B*H*D floats

    dim3 grid(HH), block(THREADS);
    prnn_fused<<<grid, block, 0, stream>>>(inputs, hidden, wih, Wa, Wb, Wc, Wd,
                                           bih, out_h, out_w);
}